// Round 6
// baseline (632.226 us; speedup 1.0000x reference)
//
#include <hip/hip_runtime.h>

#define HH 512
#define WW 512
#define NPIX (HH * WW)          // 262144
#define NIMG 16
#define KPTS 1024
#define NWORDS (NPIX / 64)      // 4096 u64 mask words per image

// ---------------------------------------------------------------------------
// Kernel 1: binarize + uniform LBP (P=8,R=1) — PURE BOOLEAN form. (unchanged)
// ---------------------------------------------------------------------------
__global__ void lbp_kernel(const float* __restrict__ mo,
                           const float* __restrict__ lb,
                           unsigned long long* __restrict__ maskbits) {
    int m = blockIdx.y;                    // image 0..15: even=pred, odd=mask
    int pix = blockIdx.x * blockDim.x + threadIdx.x;   // 0..262143
    int r = pix >> 9, c = pix & 511;
    int sample = m >> 1;
    const float* img = (m & 1) ? (lb + sample * NPIX) : (mo + sample * NPIX);
    float thr = (m & 1) ? 0.5f : 0.0f;     // sigmoid(x)>0.5 <=> x>0

    int rm = r - (r > 0), rp = r + (r < HH - 1);
    int cm = c - (c > 0), cp = c + (c < WW - 1);
    const float* rowm = img + rm * WW;
    const float* row0 = img + r  * WW;
    const float* rowp = img + rp * WW;

    bool bmm = rowm[cm] > thr, bm0 = rowm[c] > thr, bmp = rowm[cp] > thr;
    bool b0m = row0[cm] > thr, b00 = row0[c] > thr, b0p = row0[cp] > thr;
    bool bpm = rowp[cm] > thr, bp0 = rowp[c] > thr, bpp = rowp[cp] > thr;

    bool r0e = (r == 0), c0e = (c == 0);
    bool t2m = r0e ? bpm : b0m;    // B(row2, cm)
    bool t2c = r0e ? bp0 : b00;    // B(row2, c)
    bool t2p = r0e ? bpp : b0p;    // B(row2, cp)
    bool mc2 = c0e ? bmp : bm0;    // B(rm,  col2)
    bool tc2 = c0e ? t2p : t2c;    // B(row2,col2)
    bool zc2 = c0e ? b0p : b00;    // B(r,   col2)
    bool pc2 = c0e ? bpp : bp0;    // B(rp,  col2)

    unsigned bb =
        (b0p                     ?   1u : 0u)
      | ((bm0 & bmp & t2c & t2p) ?   2u : 0u)
      | (bm0                     ?   4u : 0u)
      | ((bmm & mc2 & t2m & tc2) ?   8u : 0u)
      | (b0m                     ?  16u : 0u)
      | ((b0m & zc2 & bpm & pc2) ?  32u : 0u)
      | (bp0                     ?  64u : 0u)
      | ((b0p & bp0 & bpp)       ? 128u : 0u);

    unsigned rol = ((bb << 1) | (bb >> 7)) & 0xFFu;
    int changes = __popc(bb ^ rol);
    int s = __popc(bb);
    bool maskbit = b00 && (changes <= 2) && (s < 5);   // lbp < THR(=5)

    unsigned long long w = __ballot(maskbit);
    if ((threadIdx.x & 63) == 0)
        maskbits[m * NWORDS + (pix >> 6)] = w;
}

// ---------------------------------------------------------------------------
// Kernel 2: stable row-major compaction to K=1024 packed points per image
// (unchanged)
// ---------------------------------------------------------------------------
__global__ void select_kernel(const unsigned long long* __restrict__ maskbits,
                              unsigned* __restrict__ ptsG) {
    __shared__ unsigned swv[4];
    int m = blockIdx.x, tid = threadIdx.x;
    int lane = tid & 63, wid = tid >> 6;

    for (int i = tid; i < KPTS; i += 256) ptsG[m * KPTS + i] = 0u;
    __syncthreads();

    unsigned running = 0;
    for (int ch = 0; ch < 16; ch++) {
        int w = ch * 256 + tid;
        unsigned long long word = maskbits[m * NWORDS + w];
        unsigned cnt = (unsigned)__popcll(word);

        unsigned x = cnt;                    // intra-wave inclusive scan
#pragma unroll
        for (int d = 1; d < 64; d <<= 1) {
            unsigned y = (unsigned)__shfl_up((int)x, d, 64);
            x += (lane >= d) ? y : 0u;
        }
        if (lane == 63) swv[wid] = x;
        __syncthreads();
        unsigned woff = 0, total = 0;
#pragma unroll
        for (int ww = 0; ww < 4; ww++) {
            unsigned t = swv[ww];
            total += t;
            woff += (ww < wid) ? t : 0u;
        }
        unsigned rank = running + woff + x - cnt;   // exclusive prefix
        while (word) {
            int b = __builtin_ctzll(word);
            word &= word - 1;
            if (rank < (unsigned)KPTS) {
                unsigned p = (unsigned)(w * 64 + b);
                unsigned rr = p >> 9, cc = p & 511u;
                ptsG[m * KPTS + rank] = (rr << 16) | cc;
            }
            rank++;
        }
        running += total;
        if (running >= (unsigned)KPTS) break;   // uniform -> safe
        __syncthreads();   // protect swv before next chunk
    }
}

// ---------------------------------------------------------------------------
// Kernel 3: 4-wave Prim, R1 skeleton with a de-fattened reduce/exchange:
//  (a) per-wave reduce = in-lane min4 + ONLY 4 DPP row_shr steps; the 4
//      per-row minima (lanes 15/31/47/63) ds_min_u32 into ONE LDS word ->
//      post-barrier global min = single broadcast ds_read_b32 (no combine,
//      no bcast DPP, no b128).
//  (b) no scalar round-trips: slot bools are VGPR bit-tests on vm; pj comes
//      from ds_bpermute(vm&63) instead of readfirstlane+readlane.
//  (c) 3-word rotation, ONE barrier/iter: iter i reads xw[i%3], atomics
//      target xw[(i+1)%3], tid0 resets xw[(i+2)%3]. Every conflicting pair
//      is separated by >=1 barrier:
//        reads(i) < bar(i) < reset(i+1)   [same word]
//        reset(i) < bar(i) < atomics(i+1) [same word]
//        atomics(i) < bar(i) < reads(i+1) [same word]
// Keys / idx tie-break / signed-min self-kill / edge encoding bit-identical
// to R1 => identical extraction order; recover/final unchanged.
// ---------------------------------------------------------------------------
typedef short v2s __attribute__((ext_vector_type(2)));

__device__ __forceinline__ int dist2_packed(unsigned a, unsigned b) {
#if __has_builtin(__builtin_amdgcn_sdot2)
    v2s d = __builtin_bit_cast(v2s, a) - __builtin_bit_cast(v2s, b);
    return __builtin_amdgcn_sdot2(d, d, 0, false);
#else
    int dr = (int)(a >> 16) - (int)(b >> 16);
    int dc = (int)(a & 0xFFFFu) - (int)(b & 0xFFFFu);
    return __mul24(dr, dr) + __mul24(dc, dc);
#endif
}

__device__ __forceinline__ unsigned umin3(unsigned a, unsigned b, unsigned c) {
    unsigned t = a < b ? a : b;          // fuses to v_min3_u32
    return t < c ? t : c;
}

template <int CTRL>
__device__ __forceinline__ unsigned umin_dpp(unsigned x) {
    unsigned o = (unsigned)__builtin_amdgcn_update_dpp((int)x, (int)x, CTRL,
                                                       0xf, 0xf, false);
    return o < x ? o : x;
}

// biased key: coords pre-shifted <<5 so sdot2 gives d2<<10; acc = idx-1024
__device__ __forceinline__ unsigned mk_key(unsigned ps, unsigned qs, int izb) {
#if __has_builtin(__builtin_amdgcn_sdot2)
    v2s d = __builtin_bit_cast(v2s, ps) - __builtin_bit_cast(v2s, qs);
    return (unsigned)__builtin_amdgcn_sdot2(d, d, izb, false);
#else
    int dr = (int)(short)(ps >> 16) - (int)(short)(qs >> 16);
    int dc = (int)(short)(ps & 0xFFFFu) - (int)(short)(qs & 0xFFFFu);
    return (unsigned)(dr * dr + dc * dc + izb);
#endif
}

// uniform select of points[wslot][.] from 16 replicated regs; bools b0..b3
// are VGPR-derived (uniform content)
#define SEL16(P, res)                                                     \
    { unsigned _a0 = b0 ? P##1  : P##0;                                   \
      unsigned _a1 = b0 ? P##3  : P##2;                                   \
      unsigned _a2 = b0 ? P##5  : P##4;                                   \
      unsigned _a3 = b0 ? P##7  : P##6;                                   \
      unsigned _a4 = b0 ? P##9  : P##8;                                   \
      unsigned _a5 = b0 ? P##11 : P##10;                                  \
      unsigned _a6 = b0 ? P##13 : P##12;                                  \
      unsigned _a7 = b0 ? P##15 : P##14;                                  \
      unsigned _c0 = b1 ? _a1 : _a0;                                      \
      unsigned _c1 = b1 ? _a3 : _a2;                                      \
      unsigned _c2 = b1 ? _a5 : _a4;                                      \
      unsigned _c3 = b1 ? _a7 : _a6;                                      \
      unsigned _e0 = b2 ? _c1 : _c0;                                      \
      unsigned _e1 = b2 ? _c3 : _c2;                                      \
      res = b3 ? _e1 : _e0; }

#define LOADP(P, B)                                                       \
    unsigned P##0  = B[( 0 << 6) | lane] << 5;                            \
    unsigned P##1  = B[( 1 << 6) | lane] << 5;                            \
    unsigned P##2  = B[( 2 << 6) | lane] << 5;                            \
    unsigned P##3  = B[( 3 << 6) | lane] << 5;                            \
    unsigned P##4  = B[( 4 << 6) | lane] << 5;                            \
    unsigned P##5  = B[( 5 << 6) | lane] << 5;                            \
    unsigned P##6  = B[( 6 << 6) | lane] << 5;                            \
    unsigned P##7  = B[( 7 << 6) | lane] << 5;                            \
    unsigned P##8  = B[( 8 << 6) | lane] << 5;                            \
    unsigned P##9  = B[( 9 << 6) | lane] << 5;                            \
    unsigned P##10 = B[(10 << 6) | lane] << 5;                            \
    unsigned P##11 = B[(11 << 6) | lane] << 5;                            \
    unsigned P##12 = B[(12 << 6) | lane] << 5;                            \
    unsigned P##13 = B[(13 << 6) | lane] << 5;                            \
    unsigned P##14 = B[(14 << 6) | lane] << 5;                            \
    unsigned P##15 = B[(15 << 6) | lane] << 5;

// own-slot signed-min update (dead stays dead; extracted self-kills)
#define OSU(s)                                                            \
    { unsigned _nk = mk_key(oq##s, pjs, oi##s);                           \
      ok##s = (unsigned)min((int)ok##s, (int)_nk); }

__global__ __launch_bounds__(256, 1) void mst_kernel(const unsigned* __restrict__ ptsG,
                                                     unsigned* __restrict__ edgesG) {
    __shared__ unsigned xw[3];       // rotating {read, atomic-target, reset}
    int tid = threadIdx.x;
    int lane = tid & 63, wid = tid >> 6;         // 4 waves
    int m = blockIdx.x;
    const unsigned* base = ptsG + m * KPTS;
    unsigned pt0s = base[0] << 5;                // uniform self point 0

    LOADP(p, base)                               // replicated point set

    // own key slots: global slot = wid*4 + s
    int oi0 = (((wid * 4 + 0) << 6) | lane) - 1024;
    int oi1 = (((wid * 4 + 1) << 6) | lane) - 1024;
    int oi2 = (((wid * 4 + 2) << 6) | lane) - 1024;
    int oi3 = (((wid * 4 + 3) << 6) | lane) - 1024;
    unsigned oq0 = base[((wid * 4 + 0) << 6) | lane] << 5;
    unsigned oq1 = base[((wid * 4 + 1) << 6) | lane] << 5;
    unsigned oq2 = base[((wid * 4 + 2) << 6) | lane] << 5;
    unsigned oq3 = base[((wid * 4 + 3) << 6) | lane] << 5;
    unsigned ok0 = mk_key(oq0, pt0s, oi0);       // node0 self-kills
    unsigned ok1 = mk_key(oq1, pt0s, oi1);
    unsigned ok2 = mk_key(oq2, pt0s, oi2);
    unsigned ok3 = mk_key(oq3, pt0s, oi3);

    if (tid < 3) xw[tid] = 0xFFFFFFFFu;
    __syncthreads();

    // prologue reduce -> xw[0]
    {
        unsigned r3 = umin3(ok0, ok1, ok2);
        unsigned rk = r3 < ok3 ? r3 : ok3;
        rk = umin_dpp<0x111>(rk);   // row_shr:1
        rk = umin_dpp<0x112>(rk);   // row_shr:2
        rk = umin_dpp<0x114>(rk);   // row_shr:4
        rk = umin_dpp<0x118>(rk);   // row_shr:8 -> lane15 of each 16-row
        if ((lane & 15) == 15) atomicMin(&xw[0], rk);
    }
    __syncthreads();

    unsigned* eout = edgesG + m * KPTS;
    unsigned acc = 0;
    int pa = 0, pb = 1, pc = 2;      // read / atomic-target / reset

#pragma unroll 1
    for (int chk = 0; chk < 16; chk++) {
        int tmax = (chk < 15) ? 64 : 63;     // 15*64 + 63 = 1023 iterations
#pragma unroll 1
        for (int t = 0; t < tmax; t++) {
            // ---- global min: single broadcast b32 read ----
            unsigned vm = xw[pa];

            // ---- edge record (off critical path) ----
            unsigned wkv = vm + 1024u;
            acc = (lane == t) ? wkv : acc;

            // ---- pj: SEL16 (VGPR bools) + ds_bpermute (no scalar hops) ----
            bool b0 = (vm & 64u)  != 0u;
            bool b1 = (vm & 128u) != 0u;
            bool b2 = (vm & 256u) != 0u;
            bool b3 = (vm & 512u) != 0u;
            unsigned sel;
            SEL16(p, sel);
            unsigned pjs = (unsigned)__builtin_amdgcn_ds_bpermute(
                (int)((vm << 2) & 0xFCu), (int)sel);

            // ---- decrease-key; extracted slot self-kills (d2=0 -> neg) ----
            OSU(0) OSU(1) OSU(2) OSU(3)
            unsigned r3 = umin3(ok0, ok1, ok2);
            unsigned rk = r3 < ok3 ? r3 : ok3;

            // ---- per-row reduce (4 DPP) + one-word atomic min ----
            rk = umin_dpp<0x111>(rk);
            rk = umin_dpp<0x112>(rk);
            rk = umin_dpp<0x114>(rk);
            rk = umin_dpp<0x118>(rk);
            if ((lane & 15) == 15) atomicMin(&xw[pb], rk);
            if (tid == 0) xw[pc] = 0xFFFFFFFFu;   // reset 3rd word
            __syncthreads();
            int tmp = pa; pa = pb; pb = pc; pc = tmp;   // rotate
        }
        // acc identical in all waves; rotate the chunk stores
        if (wid == (chk & 3)) eout[(chk << 6) + lane] = acc;
    }
}

// ---------------------------------------------------------------------------
// Kernel 4 (phase 2): recover src per edge + per-edge (Dp-Dm)^2. (unchanged)
// ---------------------------------------------------------------------------
__global__ void recover_kernel(const unsigned* __restrict__ ptsG,
                               const unsigned* __restrict__ edgesG,
                               float* __restrict__ contrib) {
    __shared__ unsigned sS[KPTS];
    __shared__ unsigned sO[KPTS];
    __shared__ unsigned short sT[KPTS];   // extraction time + 1 (0 = root)
    int g = blockIdx.x, m = blockIdx.y;
    int tid = threadIdx.x;
    int partner = m ^ 1;

    for (int i = tid; i < KPTS; i += 256) {
        sS[i] = ptsG[m * KPTS + i];
        sO[i] = ptsG[partner * KPTS + i];
    }
    for (int e = tid; e < KPTS - 1; e += 256) {
        unsigned wkk = edgesG[m * KPTS + e];
        sT[wkk & 1023u] = (unsigned short)(e + 1);
    }
    if (tid == 0) sT[0] = 0;
    __syncthreads();

    int lane = tid & 63, w = tid >> 6;
    for (int k = 0; k < 16; k++) {
        int e = g * 64 + w * 16 + k;
        if (e >= KPTS - 1) break;            // only e=1023 (g=15,w=3,k=15)
        unsigned wk = edgesG[m * KPTS + e];
        unsigned j = wk & 1023u;
        unsigned d2p = wk >> 10;
        unsigned pj = sS[j];
        unsigned te1 = (unsigned)(e + 1);

        unsigned best = 0xFFFFFFFFu;
#pragma unroll
        for (int i = 0; i < 16; i++) {
            int v = i * 64 + lane;
            unsigned pv = sS[v];
            int d2 = dist2_packed(pv, pj);
            unsigned tv1 = (unsigned)sT[v];
            bool qual = ((unsigned)d2 == d2p) && (tv1 < te1);
            unsigned cand = qual ? ((tv1 << 10) | (unsigned)v) : 0xFFFFFFFFu;
            best = cand < best ? cand : best;
        }
#pragma unroll
        for (int dd = 32; dd; dd >>= 1) {
            unsigned o = (unsigned)__shfl_xor((int)best, dd, 64);
            best = o < best ? o : best;
        }
        unsigned vsrc = best & 1023u;
        if (lane == 0) {
            unsigned oj = sO[j], os = sO[vsrc];
            float Dp = __fsqrt_rn((float)d2p);
            float Dm = __fsqrt_rn((float)dist2_packed(oj, os));
            float diff = Dp - Dm;
            contrib[m * (KPTS - 1) + e] = diff * diff;
        }
    }
}

// ---------------------------------------------------------------------------
// Kernel 5: per-image f64 sum (extraction order, deterministic) -> loss
// (unchanged)
// ---------------------------------------------------------------------------
__global__ void final_kernel(const float* __restrict__ contrib,
                             float* __restrict__ out) {
    __shared__ double part[NIMG];
    int t = threadIdx.x;
    if (t < NIMG) {
        double s = 0.0;
        for (int e = 0; e < KPTS - 1; e++)
            s += (double)contrib[t * (KPTS - 1) + e];
        part[t] = sqrt(s);
    }
    __syncthreads();
    if (t == 0) {
        double tot = 0.0;
        for (int i = 0; i < NIMG; i++) tot += part[i];
        out[0] = (float)(0.1 * tot / 8.0);
    }
}

// ---------------------------------------------------------------------------
// ws layout:
//   [0,512K)     maskbits (lbp->select), then DEAD:
//   [0,64K)      edgesG   (mst->recover)   — overlaps dead maskbits
//   [64K,128K)   contrib  (recover->final) — overlaps dead maskbits
//   [512K,576K)  ptsG     (select->mst/recover)
// ---------------------------------------------------------------------------
extern "C" void kernel_launch(void* const* d_in, const int* in_sizes, int n_in,
                              void* d_out, int out_size, void* d_ws, size_t ws_size,
                              hipStream_t stream) {
    const float* mo = (const float*)d_in[1];   // model_output
    const float* lb = (const float*)d_in[2];   // labels

    unsigned long long* maskbits = (unsigned long long*)d_ws;
    unsigned* edgesG = (unsigned*)d_ws;
    float* contrib = (float*)((char*)d_ws + (size_t)64 * 1024);
    unsigned* ptsG = (unsigned*)((char*)d_ws + (size_t)NIMG * NWORDS * 8);
    float* out = (float*)d_out;

    lbp_kernel<<<dim3(NPIX / 256, NIMG), 256, 0, stream>>>(mo, lb, maskbits);
    select_kernel<<<NIMG, 256, 0, stream>>>(maskbits, ptsG);
    mst_kernel<<<NIMG, 256, 0, stream>>>(ptsG, edgesG);
    recover_kernel<<<dim3(16, NIMG), 256, 0, stream>>>(ptsG, edgesG, contrib);
    final_kernel<<<1, 64, 0, stream>>>(contrib, out);
}

// Round 7
// 425.077 us; speedup vs baseline: 1.4873x; 1.4873x over previous
//
#include <hip/hip_runtime.h>

#define HH 512
#define WW 512
#define NPIX (HH * WW)          // 262144
#define NIMG 16
#define KPTS 1024
#define NWORDS (NPIX / 64)      // 4096 u64 mask words per image

// ---------------------------------------------------------------------------
// Kernel 1: binarize + uniform LBP (P=8,R=1) — PURE BOOLEAN form. (unchanged)
// ---------------------------------------------------------------------------
__global__ void lbp_kernel(const float* __restrict__ mo,
                           const float* __restrict__ lb,
                           unsigned long long* __restrict__ maskbits) {
    int m = blockIdx.y;                    // image 0..15: even=pred, odd=mask
    int pix = blockIdx.x * blockDim.x + threadIdx.x;   // 0..262143
    int r = pix >> 9, c = pix & 511;
    int sample = m >> 1;
    const float* img = (m & 1) ? (lb + sample * NPIX) : (mo + sample * NPIX);
    float thr = (m & 1) ? 0.5f : 0.0f;     // sigmoid(x)>0.5 <=> x>0

    int rm = r - (r > 0), rp = r + (r < HH - 1);
    int cm = c - (c > 0), cp = c + (c < WW - 1);
    const float* rowm = img + rm * WW;
    const float* row0 = img + r  * WW;
    const float* rowp = img + rp * WW;

    bool bmm = rowm[cm] > thr, bm0 = rowm[c] > thr, bmp = rowm[cp] > thr;
    bool b0m = row0[cm] > thr, b00 = row0[c] > thr, b0p = row0[cp] > thr;
    bool bpm = rowp[cm] > thr, bp0 = rowp[c] > thr, bpp = rowp[cp] > thr;

    bool r0e = (r == 0), c0e = (c == 0);
    bool t2m = r0e ? bpm : b0m;    // B(row2, cm)
    bool t2c = r0e ? bp0 : b00;    // B(row2, c)
    bool t2p = r0e ? bpp : b0p;    // B(row2, cp)
    bool mc2 = c0e ? bmp : bm0;    // B(rm,  col2)
    bool tc2 = c0e ? t2p : t2c;    // B(row2,col2)
    bool zc2 = c0e ? b0p : b00;    // B(r,   col2)
    bool pc2 = c0e ? bpp : bp0;    // B(rp,  col2)

    unsigned bb =
        (b0p                     ?   1u : 0u)
      | ((bm0 & bmp & t2c & t2p) ?   2u : 0u)
      | (bm0                     ?   4u : 0u)
      | ((bmm & mc2 & t2m & tc2) ?   8u : 0u)
      | (b0m                     ?  16u : 0u)
      | ((b0m & zc2 & bpm & pc2) ?  32u : 0u)
      | (bp0                     ?  64u : 0u)
      | ((b0p & bp0 & bpp)       ? 128u : 0u);

    unsigned rol = ((bb << 1) | (bb >> 7)) & 0xFFu;
    int changes = __popc(bb ^ rol);
    int s = __popc(bb);
    bool maskbit = b00 && (changes <= 2) && (s < 5);   // lbp < THR(=5)

    unsigned long long w = __ballot(maskbit);
    if ((threadIdx.x & 63) == 0)
        maskbits[m * NWORDS + (pix >> 6)] = w;
}

// ---------------------------------------------------------------------------
// Kernel 2: stable row-major compaction to K=1024 packed points per image
// (unchanged)
// ---------------------------------------------------------------------------
__global__ void select_kernel(const unsigned long long* __restrict__ maskbits,
                              unsigned* __restrict__ ptsG) {
    __shared__ unsigned swv[4];
    int m = blockIdx.x, tid = threadIdx.x;
    int lane = tid & 63, wid = tid >> 6;

    for (int i = tid; i < KPTS; i += 256) ptsG[m * KPTS + i] = 0u;
    __syncthreads();

    unsigned running = 0;
    for (int ch = 0; ch < 16; ch++) {
        int w = ch * 256 + tid;
        unsigned long long word = maskbits[m * NWORDS + w];
        unsigned cnt = (unsigned)__popcll(word);

        unsigned x = cnt;                    // intra-wave inclusive scan
#pragma unroll
        for (int d = 1; d < 64; d <<= 1) {
            unsigned y = (unsigned)__shfl_up((int)x, d, 64);
            x += (lane >= d) ? y : 0u;
        }
        if (lane == 63) swv[wid] = x;
        __syncthreads();
        unsigned woff = 0, total = 0;
#pragma unroll
        for (int ww = 0; ww < 4; ww++) {
            unsigned t = swv[ww];
            total += t;
            woff += (ww < wid) ? t : 0u;
        }
        unsigned rank = running + woff + x - cnt;   // exclusive prefix
        while (word) {
            int b = __builtin_ctzll(word);
            word &= word - 1;
            if (rank < (unsigned)KPTS) {
                unsigned p = (unsigned)(w * 64 + b);
                unsigned rr = p >> 9, cc = p & 511u;
                ptsG[m * KPTS + rank] = (rr << 16) | cc;
            }
            rank++;
        }
        running += total;
        if (running >= (unsigned)KPTS) break;   // uniform -> safe
        __syncthreads();   // protect swv before next chunk
    }
}

// ---------------------------------------------------------------------------
// Kernel 3: 4-wave Prim — EXACT R1 skeleton (best measured: 657 cy/iter),
// restored after rounds 2/3/5/6 all regressed with heavier exchange
// replacements. ONE surgical change vs R1, never implicated in any
// regression: the scalar decode is de-serialized. wk = vm + 1024 only sets
// bit 10, so bits 0..9 of vm equal j's: SEL16's b0..b3 are VGPR bit-tests
// on vm (no readfirstlane on that path), wkv stays in VGPR for the acc
// record, and readfirstlane(vm)&63 (needed only as the v_readlane index)
// runs in PARALLEL with the SEL16 tree. Key math / tie-break / self-kill /
// edge encoding bit-identical to R1 => identical extraction order.
// ---------------------------------------------------------------------------
typedef short v2s __attribute__((ext_vector_type(2)));
typedef unsigned u32x4 __attribute__((ext_vector_type(4)));

__device__ __forceinline__ int dist2_packed(unsigned a, unsigned b) {
#if __has_builtin(__builtin_amdgcn_sdot2)
    v2s d = __builtin_bit_cast(v2s, a) - __builtin_bit_cast(v2s, b);
    return __builtin_amdgcn_sdot2(d, d, 0, false);
#else
    int dr = (int)(a >> 16) - (int)(b >> 16);
    int dc = (int)(a & 0xFFFFu) - (int)(b & 0xFFFFu);
    return __mul24(dr, dr) + __mul24(dc, dc);
#endif
}

__device__ __forceinline__ unsigned umin3(unsigned a, unsigned b, unsigned c) {
    unsigned t = a < b ? a : b;          // fuses to v_min3_u32
    return t < c ? t : c;
}

template <int CTRL>
__device__ __forceinline__ unsigned umin_dpp(unsigned x) {
    unsigned o = (unsigned)__builtin_amdgcn_update_dpp((int)x, (int)x, CTRL,
                                                       0xf, 0xf, false);
    return o < x ? o : x;
}

// full-wave unsigned-min; result valid in lane 63 only.
__device__ __forceinline__ unsigned wave_min_to_lane63(unsigned x) {
    x = umin_dpp<0x111>(x);   // row_shr:1
    x = umin_dpp<0x112>(x);   // row_shr:2
    x = umin_dpp<0x114>(x);   // row_shr:4
    x = umin_dpp<0x118>(x);   // row_shr:8  -> lane15 of each 16-row
    x = umin_dpp<0x142>(x);   // row_bcast:15
    x = umin_dpp<0x143>(x);   // row_bcast:31 -> lane63 = wave min
    return x;
}

// biased key: coords pre-shifted <<5 so sdot2 gives d2<<10; acc = idx-1024
__device__ __forceinline__ unsigned mk_key(unsigned ps, unsigned qs, int izb) {
#if __has_builtin(__builtin_amdgcn_sdot2)
    v2s d = __builtin_bit_cast(v2s, ps) - __builtin_bit_cast(v2s, qs);
    return (unsigned)__builtin_amdgcn_sdot2(d, d, izb, false);
#else
    int dr = (int)(short)(ps >> 16) - (int)(short)(qs >> 16);
    int dc = (int)(short)(ps & 0xFFFFu) - (int)(short)(qs & 0xFFFFu);
    return (unsigned)(dr * dr + dc * dc + izb);
#endif
}

// uniform select of points[wslot][.] from 16 replicated regs; bools b0..b3
// in scope (VGPR-derived, uniform content)
#define SEL16(P, res)                                                     \
    { unsigned _a0 = b0 ? P##1  : P##0;                                   \
      unsigned _a1 = b0 ? P##3  : P##2;                                   \
      unsigned _a2 = b0 ? P##5  : P##4;                                   \
      unsigned _a3 = b0 ? P##7  : P##6;                                   \
      unsigned _a4 = b0 ? P##9  : P##8;                                   \
      unsigned _a5 = b0 ? P##11 : P##10;                                  \
      unsigned _a6 = b0 ? P##13 : P##12;                                  \
      unsigned _a7 = b0 ? P##15 : P##14;                                  \
      unsigned _c0 = b1 ? _a1 : _a0;                                      \
      unsigned _c1 = b1 ? _a3 : _a2;                                      \
      unsigned _c2 = b1 ? _a5 : _a4;                                      \
      unsigned _c3 = b1 ? _a7 : _a6;                                      \
      unsigned _e0 = b2 ? _c1 : _c0;                                      \
      unsigned _e1 = b2 ? _c3 : _c2;                                      \
      res = b3 ? _e1 : _e0; }

#define LOADP(P, B)                                                       \
    unsigned P##0  = B[( 0 << 6) | lane] << 5;                            \
    unsigned P##1  = B[( 1 << 6) | lane] << 5;                            \
    unsigned P##2  = B[( 2 << 6) | lane] << 5;                            \
    unsigned P##3  = B[( 3 << 6) | lane] << 5;                            \
    unsigned P##4  = B[( 4 << 6) | lane] << 5;                            \
    unsigned P##5  = B[( 5 << 6) | lane] << 5;                            \
    unsigned P##6  = B[( 6 << 6) | lane] << 5;                            \
    unsigned P##7  = B[( 7 << 6) | lane] << 5;                            \
    unsigned P##8  = B[( 8 << 6) | lane] << 5;                            \
    unsigned P##9  = B[( 9 << 6) | lane] << 5;                            \
    unsigned P##10 = B[(10 << 6) | lane] << 5;                            \
    unsigned P##11 = B[(11 << 6) | lane] << 5;                            \
    unsigned P##12 = B[(12 << 6) | lane] << 5;                            \
    unsigned P##13 = B[(13 << 6) | lane] << 5;                            \
    unsigned P##14 = B[(14 << 6) | lane] << 5;                            \
    unsigned P##15 = B[(15 << 6) | lane] << 5;

// own-slot signed-min update (dead stays dead; extracted self-kills)
#define OSU(s)                                                            \
    { unsigned _nk = mk_key(oq##s, pjs, oi##s);                           \
      ok##s = (unsigned)min((int)ok##s, (int)_nk); }

__global__ __launch_bounds__(256, 1) void mst_kernel(const unsigned* __restrict__ ptsG,
                                                     unsigned* __restrict__ edgesG) {
    __shared__ __align__(16) unsigned xm[2][4];   // parity double-buffer
    int tid = threadIdx.x;
    int lane = tid & 63, wid = tid >> 6;          // 4 waves
    int m = blockIdx.x;
    const unsigned* base = ptsG + m * KPTS;
    unsigned pt0s = base[0] << 5;                 // uniform self point 0

    LOADP(p, base)                                // replicated point set

    // own key slots: global slot = wid*4 + s
    int oi0 = (((wid * 4 + 0) << 6) | lane) - 1024;
    int oi1 = (((wid * 4 + 1) << 6) | lane) - 1024;
    int oi2 = (((wid * 4 + 2) << 6) | lane) - 1024;
    int oi3 = (((wid * 4 + 3) << 6) | lane) - 1024;
    unsigned oq0 = base[((wid * 4 + 0) << 6) | lane] << 5;
    unsigned oq1 = base[((wid * 4 + 1) << 6) | lane] << 5;
    unsigned oq2 = base[((wid * 4 + 2) << 6) | lane] << 5;
    unsigned oq3 = base[((wid * 4 + 3) << 6) | lane] << 5;
    unsigned ok0 = mk_key(oq0, pt0s, oi0);        // node0 self-kills
    unsigned ok1 = mk_key(oq1, pt0s, oi1);
    unsigned ok2 = mk_key(oq2, pt0s, oi2);
    unsigned ok3 = mk_key(oq3, pt0s, oi3);

    unsigned* eout = edgesG + m * KPTS;
    unsigned r3i = umin3(ok0, ok1, ok2);
    unsigned rk = r3i < ok3 ? r3i : ok3;   // per-lane min over own 4 slots

    unsigned acc = 0;
    int par = 0;

#pragma unroll 1
    for (int chk = 0; chk < 16; chk++) {
        int tmax = (chk < 15) ? 64 : 63;     // 15*64 + 63 = 1023 iterations
#pragma unroll 1
        for (int t = 0; t < tmax; t++) {
            // ---- per-wave reduce (6 DPP, result in lane63) + exchange ----
            unsigned wm = wave_min_to_lane63(rk);
            if (lane == 63) xm[par][wid] = wm;
            __syncthreads();

            // ---- cross-wave combine: broadcast b128 read of 4 minima ----
            u32x4 xv = *reinterpret_cast<const u32x4*>(&xm[par][0]);
            unsigned vmab = xv.x < xv.y ? xv.x : xv.y;
            unsigned vmcd = xv.z < xv.w ? xv.z : xv.w;
            unsigned vm = vmab < vmcd ? vmab : vmcd;   // uniform-content VGPR
            par ^= 1;

            // ---- de-serialized decode (vs R1):
            //      scalar path: readfirstlane only for the readlane index,
            //      runs in PARALLEL with the VGPR SEL16 tree below
            int wl = __builtin_amdgcn_readfirstlane((int)vm) & 63;

            //      vector path: wk + slot bools straight from vm (the +1024
            //      only sets bit 10; bits 0..9 are j's)
            unsigned wkv = vm + 1024u;
            bool b0 = (vm & 64u)  != 0u;
            bool b1 = (vm & 128u) != 0u;
            bool b2 = (vm & 256u) != 0u;
            bool b3 = (vm & 512u) != 0u;
            unsigned sel;
            SEL16(p, sel);
            unsigned pjs = (unsigned)__builtin_amdgcn_readlane((int)sel, wl);

            // ---- edge record: cndmask accumulate into lane t ----
            acc = (lane == t) ? wkv : acc;

            // ---- decrease-key; extracted slot self-kills (d2=0 -> neg) ----
            OSU(0) OSU(1) OSU(2) OSU(3)
            unsigned r3 = umin3(ok0, ok1, ok2);
            rk = r3 < ok3 ? r3 : ok3;        // next iteration's per-lane min
        }
        // acc identical in all waves; wave 0 does the coalesced batch store.
        // chk=15 lane63 writes eout[1023] (stale) — never read downstream.
        if (wid == 0) eout[(chk << 6) + lane] = acc;
    }
}

// ---------------------------------------------------------------------------
// Kernel 4 (phase 2): recover src per edge + per-edge (Dp-Dm)^2. (unchanged)
// ---------------------------------------------------------------------------
__global__ void recover_kernel(const unsigned* __restrict__ ptsG,
                               const unsigned* __restrict__ edgesG,
                               float* __restrict__ contrib) {
    __shared__ unsigned sS[KPTS];
    __shared__ unsigned sO[KPTS];
    __shared__ unsigned short sT[KPTS];   // extraction time + 1 (0 = root)
    int g = blockIdx.x, m = blockIdx.y;
    int tid = threadIdx.x;
    int partner = m ^ 1;

    for (int i = tid; i < KPTS; i += 256) {
        sS[i] = ptsG[m * KPTS + i];
        sO[i] = ptsG[partner * KPTS + i];
    }
    for (int e = tid; e < KPTS - 1; e += 256) {
        unsigned wkk = edgesG[m * KPTS + e];
        sT[wkk & 1023u] = (unsigned short)(e + 1);
    }
    if (tid == 0) sT[0] = 0;
    __syncthreads();

    int lane = tid & 63, w = tid >> 6;
    for (int k = 0; k < 16; k++) {
        int e = g * 64 + w * 16 + k;
        if (e >= KPTS - 1) break;            // only e=1023 (g=15,w=3,k=15)
        unsigned wk = edgesG[m * KPTS + e];
        unsigned j = wk & 1023u;
        unsigned d2p = wk >> 10;
        unsigned pj = sS[j];
        unsigned te1 = (unsigned)(e + 1);

        unsigned best = 0xFFFFFFFFu;
#pragma unroll
        for (int i = 0; i < 16; i++) {
            int v = i * 64 + lane;
            unsigned pv = sS[v];
            int d2 = dist2_packed(pv, pj);
            unsigned tv1 = (unsigned)sT[v];
            bool qual = ((unsigned)d2 == d2p) && (tv1 < te1);
            unsigned cand = qual ? ((tv1 << 10) | (unsigned)v) : 0xFFFFFFFFu;
            best = cand < best ? cand : best;
        }
#pragma unroll
        for (int dd = 32; dd; dd >>= 1) {
            unsigned o = (unsigned)__shfl_xor((int)best, dd, 64);
            best = o < best ? o : best;
        }
        unsigned vsrc = best & 1023u;
        if (lane == 0) {
            unsigned oj = sO[j], os = sO[vsrc];
            float Dp = __fsqrt_rn((float)d2p);
            float Dm = __fsqrt_rn((float)dist2_packed(oj, os));
            float diff = Dp - Dm;
            contrib[m * (KPTS - 1) + e] = diff * diff;
        }
    }
}

// ---------------------------------------------------------------------------
// Kernel 5: per-image f64 sum (extraction order, deterministic) -> loss
// (unchanged)
// ---------------------------------------------------------------------------
__global__ void final_kernel(const float* __restrict__ contrib,
                             float* __restrict__ out) {
    __shared__ double part[NIMG];
    int t = threadIdx.x;
    if (t < NIMG) {
        double s = 0.0;
        for (int e = 0; e < KPTS - 1; e++)
            s += (double)contrib[t * (KPTS - 1) + e];
        part[t] = sqrt(s);
    }
    __syncthreads();
    if (t == 0) {
        double tot = 0.0;
        for (int i = 0; i < NIMG; i++) tot += part[i];
        out[0] = (float)(0.1 * tot / 8.0);
    }
}

// ---------------------------------------------------------------------------
// ws layout:
//   [0,512K)     maskbits (lbp->select), then DEAD:
//   [0,64K)      edgesG   (mst->recover)   — overlaps dead maskbits
//   [64K,128K)   contrib  (recover->final) — overlaps dead maskbits
//   [512K,576K)  ptsG     (select->mst/recover)
// ---------------------------------------------------------------------------
extern "C" void kernel_launch(void* const* d_in, const int* in_sizes, int n_in,
                              void* d_out, int out_size, void* d_ws, size_t ws_size,
                              hipStream_t stream) {
    const float* mo = (const float*)d_in[1];   // model_output
    const float* lb = (const float*)d_in[2];   // labels

    unsigned long long* maskbits = (unsigned long long*)d_ws;
    unsigned* edgesG = (unsigned*)d_ws;
    float* contrib = (float*)((char*)d_ws + (size_t)64 * 1024);
    unsigned* ptsG = (unsigned*)((char*)d_ws + (size_t)NIMG * NWORDS * 8);
    float* out = (float*)d_out;

    lbp_kernel<<<dim3(NPIX / 256, NIMG), 256, 0, stream>>>(mo, lb, maskbits);
    select_kernel<<<NIMG, 256, 0, stream>>>(maskbits, ptsG);
    mst_kernel<<<NIMG, 256, 0, stream>>>(ptsG, edgesG);
    recover_kernel<<<dim3(16, NIMG), 256, 0, stream>>>(ptsG, edgesG, contrib);
    final_kernel<<<1, 64, 0, stream>>>(contrib, out);
}